// Round 1
// baseline (204.359 us; speedup 1.0000x reference)
//
#include <hip/hip_runtime.h>
#include <stdint.h>

// FeedForward_12421045420273: LIF -> 1x1conv(512->2048) -> BN -> LIF -> 1x1conv(2048->512) -> BN -> +x
// T=4 B=32 C=512 Ch=2048 H*W=196.  All-fp32 reference; we use bf16 MFMA with
// split-hi/lo W1 (fp32-accurate GEMM1 so LIF2 spike decisions don't flip) and
// plain bf16 W2 (error adds linearly, ~1e-3 << 0.11 threshold).

typedef __bf16 bf16x8 __attribute__((ext_vector_type(8)));
typedef float f32x4 __attribute__((ext_vector_type(4)));
typedef float f32x2 __attribute__((ext_vector_type(2)));

#define TPLANE 3211264u     // B*C*HW = 32*512*196
#define NCOL   6272u        // B*HW
#define MFMA_BF16 __builtin_amdgcn_mfma_f32_16x16x32_bf16

static __device__ __forceinline__ uint16_t f2bf(float f) {
  union { float f; uint32_t u; } v; v.f = f;
  return (uint16_t)((v.u + 0x7FFFu + ((v.u >> 16) & 1u)) >> 16);  // RNE
}
static __device__ __forceinline__ float bf2f(uint16_t h) {
  union { uint32_t u; float f; } v; v.u = ((uint32_t)h) << 16;
  return v.f;
}
static __device__ __forceinline__ void async16(const void* g, void* l) {
  __builtin_amdgcn_global_load_lds((const __attribute__((address_space(1))) uint32_t*)g,
                                   (__attribute__((address_space(3))) uint32_t*)l, 16, 0, 0);
}

// ---------------------------------------------------------------------------
// prep: W1 -> split hi/lo bf16 interleaved rows [4096][512]; W2 -> bf16;
// BN constants folded to scale/bias.
__global__ void prep_kernel(const float* __restrict__ W1, const float* __restrict__ W2,
                            const float* __restrict__ g1, const float* __restrict__ b1,
                            const float* __restrict__ m1, const float* __restrict__ v1,
                            const float* __restrict__ g2, const float* __restrict__ b2,
                            const float* __restrict__ m2, const float* __restrict__ v2,
                            uint16_t* __restrict__ Ws, uint16_t* __restrict__ W2b,
                            float* __restrict__ scale1, float* __restrict__ bias1,
                            float* __restrict__ scale2, float* __restrict__ bias2) {
  uint32_t i = blockIdx.x * 512u + threadIdx.x;   // exactly 2048*512 threads
  uint32_t o = i >> 9, c = i & 511u;
  float w = W1[i];
  uint16_t hi = f2bf(w);
  uint16_t lo = f2bf(w - bf2f(hi));
  Ws[(size_t)(2u * o) * 512u + c] = hi;
  Ws[(size_t)(2u * o + 1u) * 512u + c] = lo;
  W2b[i] = f2bf(W2[i]);
  if (i < 2048u) { float s = g1[i] / sqrtf(v1[i] + 1e-5f); scale1[i] = s; bias1[i] = b1[i] - m1[i] * s; }
  if (i < 512u)  { float s = g2[i] / sqrtf(v2[i] + 1e-5f); scale2[i] = s; bias2[i] = b2[i] - m2[i] * s; }
}

// ---------------------------------------------------------------------------
// LIF over input (bit-exact fp32 scan), emitting spikes bf16 in K-blocked
// GEMM layout: s1[cblk:64][t:4][n:6272][e:8], chunk = (cblk*4+t)*6272+n (16B).
// LDS transpose: coalesced reads (n fastest) -> coalesced 16B writes.
__global__ void lif1_kernel(const float* __restrict__ x, uint16_t* __restrict__ s1) {
  __shared__ __align__(16) uint16_t sl[64 * 66 * 4];   // [c:64][n:66 pad][t:4]
  const uint32_t tid = threadIdx.x;
  const uint32_t c0 = blockIdx.x * 64u;
  const uint32_t n0 = blockIdx.y * 64u;
  #pragma unroll
  for (int j = 0; j < 16; ++j) {
    uint32_t idx = (uint32_t)j * 256u + tid;
    uint32_t cl = idx >> 6, nl = idx & 63u;
    uint32_t n = n0 + nl;
    uint32_t b = n / 196u, hw = n - b * 196u;
    const float* px = x + (size_t)(b * 512u + c0 + cl) * 196u + hw;
    float v = 0.f;
    uint16_t sp[4];
    #pragma unroll
    for (int t = 0; t < 4; ++t) {
      float xv = px[(size_t)t * TPLANE];
      v += (xv - v) * 0.5f;                // exact: *0.5 never rounds
      bool s = (v >= 1.0f);
      sp[t] = s ? (uint16_t)0x3F80u : (uint16_t)0u;
      v = s ? 0.f : v;
    }
    uint2 pk;
    pk.x = (uint32_t)sp[0] | ((uint32_t)sp[1] << 16);
    pk.y = (uint32_t)sp[2] | ((uint32_t)sp[3] << 16);
    *(uint2*)&sl[(cl * 66u + nl) * 4u] = pk;
  }
  __syncthreads();
  #pragma unroll
  for (int j = 0; j < 8; ++j) {
    uint32_t id = (uint32_t)j * 256u + tid;
    uint32_t nl = id & 63u, t = (id >> 6) & 3u, cb = id >> 8;
    uint32_t us[4];
    #pragma unroll
    for (int e = 0; e < 4; ++e) {
      uint32_t lo16 = sl[((cb * 8u + 2u * e) * 66u + nl) * 4u + t];
      uint32_t hi16 = sl[((cb * 8u + 2u * e + 1u) * 66u + nl) * 4u + t];
      us[e] = lo16 | (hi16 << 16);
    }
    uint32_t chunk = (((c0 >> 3) + cb) * 4u + t) * NCOL + n0 + nl;
    uint4 o4; o4.x = us[0]; o4.y = us[1]; o4.z = us[2]; o4.w = us[3];
    *(uint4*)(s1 + (size_t)chunk * 8u) = o4;
  }
}

// ---------------------------------------------------------------------------
// GEMM1 (M'=4096 split rows, K=512, N=4t x 6272n) fused BN1 + LIF2 scan in
// registers; emits s2 spikes bf16 in the same K-blocked layout [chblk][t][n][8].
// Block tile: M'128 x (4t x 64n), BK=64, 8 waves (2M x 4N).
__launch_bounds__(512)
__global__ void gemm1_lif2_kernel(const uint16_t* __restrict__ Ws,
                                  const uint16_t* __restrict__ s1,
                                  const float* __restrict__ scale1,
                                  const float* __restrict__ bias1,
                                  uint16_t* __restrict__ s2) {
  __shared__ __align__(16) char lds[49152];
  char* ldsA = lds;               // 16KB: [i:128][q':8]*16B, q' = q ^ (i&7)
  char* ldsB = lds + 16384;       // 32KB: [kblk:8][t:4][dn:64]*16B
  const uint32_t tid = threadIdx.x;
  const uint32_t wid = tid >> 6;
  const uint32_t lane = tid & 63u;
  const uint32_t il = lane & 15u, g = lane >> 4;
  const uint32_t wm = wid >> 2, wn = wid & 3u;
  const uint32_t m0 = blockIdx.x * 128u;   // over M'=4096
  const uint32_t n0 = blockIdx.y * 64u;    // over n=6272

  f32x4 acc[4][4];                         // [fm][t]
  const f32x4 z = {0.f, 0.f, 0.f, 0.f};
  #pragma unroll
  for (int fm = 0; fm < 4; ++fm)
    #pragma unroll
    for (int t = 0; t < 4; ++t) acc[fm][t] = z;

  for (int kt = 0; kt < 8; ++kt) {
    const uint32_t k0 = (uint32_t)kt * 64u;
    #pragma unroll
    for (uint32_t r = 0; r < 2; ++r) {     // A tile: 1024 16B chunks
      uint32_t cid = r * 512u + tid;
      uint32_t i = cid >> 3, q = cid & 7u;
      const char* src = (const char*)Ws + (size_t)(m0 + i) * 1024u + (size_t)k0 * 2u
                        + (size_t)((q ^ (i & 7u)) * 16u);
      async16(src, ldsA + (r * 512u + wid * 64u) * 16u);
    }
    #pragma unroll
    for (uint32_t r = 0; r < 4; ++r) {     // B tile: 2048 16B chunks
      uint32_t cid = r * 512u + tid;
      uint32_t kb = cid >> 8, rem = cid & 255u;
      uint32_t tt = rem >> 6, dn = rem & 63u;
      const char* src = (const char*)s1
          + (size_t)((((k0 >> 3) + kb) * 4u + tt) * NCOL + n0 + dn) * 16u;
      async16(src, ldsB + (r * 512u + wid * 64u) * 16u);
    }
    __syncthreads();
    #pragma unroll
    for (int ks = 0; ks < 2; ++ks) {
      bf16x8 af[4], bfr[4];
      #pragma unroll
      for (int fm = 0; fm < 4; ++fm) {
        uint32_t i = wm * 64u + (uint32_t)fm * 16u + il;
        uint32_t q = (uint32_t)ks * 4u + g;
        af[fm] = *(const bf16x8*)(ldsA + (i * 8u + (q ^ (i & 7u))) * 16u);
      }
      #pragma unroll
      for (int t = 0; t < 4; ++t) {
        uint32_t ch = (((uint32_t)ks * 4u + g) * 4u + (uint32_t)t) * 64u + wn * 16u + il;
        bfr[t] = *(const bf16x8*)(ldsB + ch * 16u);
      }
      #pragma unroll
      for (int fm = 0; fm < 4; ++fm)
        #pragma unroll
        for (int t = 0; t < 4; ++t)
          acc[fm][t] = MFMA_BF16(af[fm], bfr[t], acc[fm][t], 0, 0, 0);
    }
    __syncthreads();
  }

  // epilogue: combine hi/lo row pairs, BN1, LIF2 scan over t (all in regs)
  const uint32_t n = n0 + wn * 16u + il;
  #pragma unroll
  for (int fm = 0; fm < 4; ++fm) {
    uint32_t oo = (m0 >> 1) + wm * 32u + (uint32_t)fm * 8u + 2u * g;  // output ch pair base
    f32x2 sc = *(const f32x2*)&scale1[oo];
    f32x2 bi = *(const f32x2*)&bias1[oo];
    float v0 = 0.f, v1 = 0.f;
    uint32_t outw[4];
    #pragma unroll
    for (int t = 0; t < 4; ++t) {
      float hb0 = (acc[fm][t][0] + acc[fm][t][1]) * sc[0] + bi[0];
      float hb1 = (acc[fm][t][2] + acc[fm][t][3]) * sc[1] + bi[1];
      v0 += (hb0 - v0) * 0.5f; bool s0 = (v0 >= 1.0f); v0 = s0 ? 0.f : v0;
      v1 += (hb1 - v1) * 0.5f; bool s1v = (v1 >= 1.0f); v1 = s1v ? 0.f : v1;
      outw[t] = (s0 ? 0x3F80u : 0u) | (s1v ? 0x3F800000u : 0u);
    }
    #pragma unroll
    for (int t = 0; t < 4; ++t) {
      size_t off = (size_t)(((oo >> 3) * 4u + (uint32_t)t) * NCOL + n) * 16u + (size_t)((oo & 7u) * 2u);
      *(uint32_t*)((char*)s2 + off) = outw[t];
    }
  }
}

// ---------------------------------------------------------------------------
// GEMM2 (M=512, K=2048, N=4t x 6272n) fused BN2 + residual + transposed
// fp32 output via per-wave LDS transpose.
__launch_bounds__(512)
__global__ void gemm2_out_kernel(const uint16_t* __restrict__ W2b,
                                 const uint16_t* __restrict__ s2,
                                 const float* __restrict__ scale2,
                                 const float* __restrict__ bias2,
                                 const float* __restrict__ xin,
                                 float* __restrict__ outp) {
  __shared__ __align__(16) char lds[49152];
  char* ldsA = lds;
  char* ldsB = lds + 16384;
  float* ep = (float*)lds;        // epilogue reuse: [wave:8][c_l:16][t:4][n:20 pad] fp32
  const uint32_t tid = threadIdx.x;
  const uint32_t wid = tid >> 6;
  const uint32_t lane = tid & 63u;
  const uint32_t il = lane & 15u, g = lane >> 4;
  const uint32_t wm = wid >> 2, wn = wid & 3u;
  const uint32_t m0 = blockIdx.x * 128u;   // over C=512
  const uint32_t n0 = blockIdx.y * 64u;

  f32x4 acc[4][4];
  const f32x4 z = {0.f, 0.f, 0.f, 0.f};
  #pragma unroll
  for (int fm = 0; fm < 4; ++fm)
    #pragma unroll
    for (int t = 0; t < 4; ++t) acc[fm][t] = z;

  for (int kt = 0; kt < 32; ++kt) {
    const uint32_t k0 = (uint32_t)kt * 64u;
    #pragma unroll
    for (uint32_t r = 0; r < 2; ++r) {
      uint32_t cid = r * 512u + tid;
      uint32_t i = cid >> 3, q = cid & 7u;
      const char* src = (const char*)W2b + (size_t)(m0 + i) * 4096u + (size_t)k0 * 2u
                        + (size_t)((q ^ (i & 7u)) * 16u);
      async16(src, ldsA + (r * 512u + wid * 64u) * 16u);
    }
    #pragma unroll
    for (uint32_t r = 0; r < 4; ++r) {
      uint32_t cid = r * 512u + tid;
      uint32_t kb = cid >> 8, rem = cid & 255u;
      uint32_t tt = rem >> 6, dn = rem & 63u;
      const char* src = (const char*)s2
          + (size_t)((((k0 >> 3) + kb) * 4u + tt) * NCOL + n0 + dn) * 16u;
      async16(src, ldsB + (r * 512u + wid * 64u) * 16u);
    }
    __syncthreads();
    #pragma unroll
    for (int ks = 0; ks < 2; ++ks) {
      bf16x8 af[4], bfr[4];
      #pragma unroll
      for (int fm = 0; fm < 4; ++fm) {
        uint32_t i = wm * 64u + (uint32_t)fm * 16u + il;
        uint32_t q = (uint32_t)ks * 4u + g;
        af[fm] = *(const bf16x8*)(ldsA + (i * 8u + (q ^ (i & 7u))) * 16u);
      }
      #pragma unroll
      for (int t = 0; t < 4; ++t) {
        uint32_t ch = (((uint32_t)ks * 4u + g) * 4u + (uint32_t)t) * 64u + wn * 16u + il;
        bfr[t] = *(const bf16x8*)(ldsB + ch * 16u);
      }
      #pragma unroll
      for (int fm = 0; fm < 4; ++fm)
        #pragma unroll
        for (int t = 0; t < 4; ++t)
          acc[fm][t] = MFMA_BF16(af[fm], bfr[t], acc[fm][t], 0, 0, 0);
    }
    __syncthreads();
  }

  // epilogue: BN2 + residual + write out[t][b][c][hw], LDS transpose per fm
  const uint32_t rem = tid & 63u;
  const uint32_t c_l = rem >> 2, sub = rem & 3u;
  #pragma unroll
  for (int fm = 0; fm < 4; ++fm) {
    uint32_t cbase = m0 + wm * 64u + (uint32_t)fm * 16u;
    f32x4 sc = *(const f32x4*)&scale2[cbase + 4u * g];
    f32x4 bi = *(const f32x4*)&bias2[cbase + 4u * g];
    #pragma unroll
    for (int t = 0; t < 4; ++t)
      #pragma unroll
      for (int r = 0; r < 4; ++r)
        ep[wid * 1280u + ((4u * g + (uint32_t)r) * 4u + (uint32_t)t) * 20u + il]
            = acc[fm][t][r] * sc[r] + bi[r];
    __syncthreads();
    #pragma unroll
    for (int t = 0; t < 4; ++t) {
      f32x4 val = *(const f32x4*)&ep[wid * 1280u + (c_l * 4u + (uint32_t)t) * 20u + sub * 4u];
      uint32_t nn = n0 + wn * 16u + sub * 4u;
      uint32_t b = nn / 196u, hw = nn - b * 196u;
      uint32_t c = m0 + wm * 64u + (uint32_t)fm * 16u + c_l;
      size_t off = (((size_t)t * 32u + b) * 512u + c) * 196u + hw;
      f32x4 iv = *(const f32x4*)(xin + off);
      val = val + iv;
      *(f32x4*)(outp + off) = val;
    }
    __syncthreads();
  }
}

// ---------------------------------------------------------------------------
extern "C" void kernel_launch(void* const* d_in, const int* in_sizes, int n_in,
                              void* d_out, int out_size, void* d_ws, size_t ws_size,
                              hipStream_t stream) {
  const float* x  = (const float*)d_in[0];
  const float* W1 = (const float*)d_in[1];
  const float* g1 = (const float*)d_in[2];
  const float* b1 = (const float*)d_in[3];
  const float* m1 = (const float*)d_in[4];
  const float* v1 = (const float*)d_in[5];
  const float* W2 = (const float*)d_in[6];
  const float* g2 = (const float*)d_in[7];
  const float* b2 = (const float*)d_in[8];
  const float* m2 = (const float*)d_in[9];
  const float* v2 = (const float*)d_in[10];
  float* out = (float*)d_out;
  char* ws = (char*)d_ws;

  // workspace layout (all 16B aligned), total 134,762,496 B
  uint16_t* s2b    = (uint16_t*)(ws);                    // 102,760,448  [256][4][6272][8] bf16
  uint16_t* s1b    = (uint16_t*)(ws + 102760448);        //  25,690,112  [64][4][6272][8] bf16
  uint16_t* Wsb    = (uint16_t*)(ws + 128450560);        //   4,194,304  [4096][512] bf16 hi/lo
  uint16_t* W2bb   = (uint16_t*)(ws + 132644864);        //   2,097,152  [512][2048] bf16
  float*    scale1 = (float*)(ws + 134742016);
  float*    bias1  = (float*)(ws + 134750208);
  float*    scale2 = (float*)(ws + 134758400);
  float*    bias2  = (float*)(ws + 134760448);

  prep_kernel<<<2048, 512, 0, stream>>>(W1, W2, g1, b1, m1, v1, g2, b2, m2, v2,
                                        Wsb, W2bb, scale1, bias1, scale2, bias2);
  lif1_kernel<<<dim3(8, 98), 256, 0, stream>>>(x, s1b);
  gemm1_lif2_kernel<<<dim3(32, 98), 512, 0, stream>>>(Wsb, s1b, scale1, bias1, s2b);
  gemm2_out_kernel<<<dim3(4, 98), 512, 0, stream>>>(W2bb, s2b, scale2, bias2, x, out);
}